// Round 11
// baseline (221.835 us; speedup 1.0000x reference)
//
#include <hip/hip_runtime.h>
#include <math.h>

typedef unsigned short ushort_t;
typedef __attribute__((ext_vector_type(8))) short short8;
typedef __attribute__((ext_vector_type(4))) float f32x4;

#define MFMA(a,b,c) __builtin_amdgcn_mfma_f32_16x16x32_bf16((a),(b),(c),0,0,0)

// Problem constants
#define BB 8
#define SS 1024
#define DD 512
#define HH 8
#define CC 64
#define PP 2047   // 2S-1

// Packed fp32x2 -> bf16x2 (RNE), single HW instruction. Bit-identical to the
// RNE bit-twiddle for normal inputs (validated: v5 staging swap, absmax same).
static __device__ __forceinline__ unsigned pack2(float a, float b) {
    unsigned r;
    asm("v_cvt_pk_bf16_f32 %0, %1, %2" : "=v"(r) : "v"(a), "v"(b));
    return r;
}
// Scalar fp32 -> bf16 (RNE) via the same instruction (1 VALU vs ~4).
static __device__ __forceinline__ ushort_t f2bf(float f) {
    unsigned r;
    asm("v_cvt_pk_bf16_f32 %0, %1, %2" : "=v"(r) : "v"(f), "v"(f));
    return (ushort_t)r;
}

// ---------------------------------------------------------------------------
// Weight transpose+cast: W[k][n] fp32 -> Wt[n][k] bf16, 5 weights.
// ---------------------------------------------------------------------------
__global__ __launch_bounds__(256) void wtrans_kernel(
    const float* __restrict__ Wq, const float* __restrict__ Wk,
    const float* __restrict__ Wv, const float* __restrict__ Wp,
    const float* __restrict__ Wo, ushort_t* __restrict__ wt)
{
    __shared__ float T[64][65];
    const int bid = blockIdx.x, tid = threadIdx.x;
    const int wi   = bid >> 6;
    const int tile = bid & 63;
    const float* Wsrc = (wi == 0) ? Wq : (wi == 1) ? Wk : (wi == 2) ? Wv
                      : (wi == 3) ? Wp : Wo;
    ushort_t* Wdst = wt + (size_t)wi * 262144;
    const int tk0 = (tile >> 3) * 64, tn0 = (tile & 7) * 64;
    const int r = tid >> 2, c4 = (tid & 3) * 16;
    #pragma unroll
    for (int rep = 0; rep < 4; ++rep) {
        float4 f = *(const float4*)(Wsrc + (size_t)(tk0 + r) * 512 + tn0 + c4 + rep * 4);
        T[r][c4 + rep * 4 + 0] = f.x; T[r][c4 + rep * 4 + 1] = f.y;
        T[r][c4 + rep * 4 + 2] = f.z; T[r][c4 + rep * 4 + 3] = f.w;
    }
    __syncthreads();
    #pragma unroll
    for (int rep = 0; rep < 4; ++rep) {
        uint2 u;
        u.x = pack2(T[c4 + rep * 4 + 0][r], T[c4 + rep * 4 + 1][r]);
        u.y = pack2(T[c4 + rep * 4 + 2][r], T[c4 + rep * 4 + 3][r]);
        *(uint2*)(Wdst + (size_t)(tn0 + r) * 512 + tk0 + c4 + rep * 4) = u;
    }
}

// ---------------------------------------------------------------------------
// Fused Q/K/V/pos projection. 64(m)x128(n) tiles, 1664 blocks, XCD swizzle.
// VGPR-prefetch double-buffering. 4 waves, each m64 x n32 (4x2 frags). BK=64.
// fp32->bf16 cast via v_cvt_pk_bf16_f32.
// ---------------------------------------------------------------------------
__global__ __launch_bounds__(256) void qkvpos_kernel(
    const float* __restrict__ Xq, const float* __restrict__ Xk,
    const float* __restrict__ Xv, const float* __restrict__ Xp,
    const ushort_t* __restrict__ wt,
    const float* __restrict__ bq, const float* __restrict__ bk,
    const float* __restrict__ bv,
    const float* __restrict__ ub, const float* __restrict__ vbias,
    ushort_t* __restrict__ qu, ushort_t* __restrict__ qvo,
    ushort_t* __restrict__ kbuf, ushort_t* __restrict__ vtb,
    ushort_t* __restrict__ pbuf)
{
    __shared__ __align__(16) ushort_t smem[64 * 72 + 128 * 72];
    ushort_t (*Xs)[72] = (ushort_t(*)[72])smem;            // [64][72]
    ushort_t (*Ws)[72] = (ushort_t(*)[72])(smem + 64 * 72);// [128][72]
    ushort_t (*Es)[136] = (ushort_t(*)[136])smem;          // epilogue [64][136]
    ushort_t (*EsT)[72] = (ushort_t(*)[72])smem;           // epilogue T [128][72]

    const int tid = threadIdx.x;
    const int wave = tid >> 6, lane = tid & 63, quad = lane >> 4, l16 = lane & 15;
    const int bid = blockIdx.x;
    const int nt = (bid >> 3) & 3;
    const int mt = (bid & 7) + 8 * (bid >> 5);
    const int n0 = nt * 128;
    int mode, mtl;
    if (mt < 128)      { mode = 0; mtl = mt; }
    else if (mt < 256) { mode = 1; mtl = mt - 128; }
    else if (mt < 384) { mode = 2; mtl = mt - 256; }
    else               { mode = 3; mtl = mt - 384; }
    const int m0 = mtl * 64;
    const float* X = (mode == 0) ? Xq : (mode == 1) ? Xk : (mode == 2) ? Xv : Xp;
    const ushort_t* W = wt + (size_t)mode * 262144;

    f32x4 acc[4][2];
    #pragma unroll
    for (int i = 0; i < 4; ++i)
        #pragma unroll
        for (int j = 0; j < 2; ++j) acc[i][j] = (f32x4){0.f, 0.f, 0.f, 0.f};

    const int xr = tid >> 2, xc = (tid & 3) * 16;   // X stage: 4 thr/row
    int xrow = m0 + xr;
    if (mode == 3 && xrow > PP - 1) xrow = PP - 1;
    const int wr0 = tid >> 2, wc0 = (tid & 3) * 16;          // W i=0
    const int wr1 = (tid + 256) >> 2, wc1 = wc0;             // W i=1

    // ---- initial stage k0=0 ----
    {
        const float* xp = X + (size_t)xrow * 512 + xc;
        float4 f0 = *(const float4*)xp;
        float4 f1 = *(const float4*)(xp + 4);
        float4 f2 = *(const float4*)(xp + 8);
        float4 f3 = *(const float4*)(xp + 12);
        uint4 a, bpk;
        a.x = pack2(f0.x, f0.y); a.y = pack2(f0.z, f0.w);
        a.z = pack2(f1.x, f1.y); a.w = pack2(f1.z, f1.w);
        bpk.x = pack2(f2.x, f2.y); bpk.y = pack2(f2.z, f2.w);
        bpk.z = pack2(f3.x, f3.y); bpk.w = pack2(f3.z, f3.w);
        *(uint4*)&Xs[xr][xc] = a;
        *(uint4*)&Xs[xr][xc + 8] = bpk;
        const ushort_t* wp0 = W + (size_t)(n0 + wr0) * 512 + wc0;
        const ushort_t* wp1 = W + (size_t)(n0 + wr1) * 512 + wc1;
        *(uint4*)&Ws[wr0][wc0]     = *(const uint4*)wp0;
        *(uint4*)&Ws[wr0][wc0 + 8] = *(const uint4*)(wp0 + 8);
        *(uint4*)&Ws[wr1][wc1]     = *(const uint4*)wp1;
        *(uint4*)&Ws[wr1][wc1 + 8] = *(const uint4*)(wp1 + 8);
    }
    __syncthreads();

    for (int k0 = 0; k0 < 512; k0 += 64) {
        const bool more = (k0 + 64) < 512;
        // ---- prefetch next k-tile into VGPRs (overlaps compute below) ----
        uint4 xa, xb, wv0a, wv0b, wv1a, wv1b;
        if (more) {
            const float* xp = X + (size_t)xrow * 512 + k0 + 64 + xc;
            float4 f0 = *(const float4*)xp;
            float4 f1 = *(const float4*)(xp + 4);
            float4 f2 = *(const float4*)(xp + 8);
            float4 f3 = *(const float4*)(xp + 12);
            xa.x = pack2(f0.x, f0.y); xa.y = pack2(f0.z, f0.w);
            xa.z = pack2(f1.x, f1.y); xa.w = pack2(f1.z, f1.w);
            xb.x = pack2(f2.x, f2.y); xb.y = pack2(f2.z, f2.w);
            xb.z = pack2(f3.x, f3.y); xb.w = pack2(f3.z, f3.w);
            const ushort_t* wp0 = W + (size_t)(n0 + wr0) * 512 + k0 + 64 + wc0;
            const ushort_t* wp1 = W + (size_t)(n0 + wr1) * 512 + k0 + 64 + wc1;
            wv0a = *(const uint4*)wp0; wv0b = *(const uint4*)(wp0 + 8);
            wv1a = *(const uint4*)wp1; wv1b = *(const uint4*)(wp1 + 8);
        }
        // ---- compute on current LDS tile ----
        #pragma unroll
        for (int kk = 0; kk < 2; ++kk) {
            short8 av[4], bv4[2];
            #pragma unroll
            for (int ms = 0; ms < 4; ++ms)
                av[ms] = *(const short8*)&Xs[ms * 16 + l16][kk * 32 + quad * 8];
            #pragma unroll
            for (int ns = 0; ns < 2; ++ns)
                bv4[ns] = *(const short8*)&Ws[wave * 32 + ns * 16 + l16][kk * 32 + quad * 8];
            #pragma unroll
            for (int ms = 0; ms < 4; ++ms)
                #pragma unroll
                for (int ns = 0; ns < 2; ++ns)
                    acc[ms][ns] = MFMA(av[ms], bv4[ns], acc[ms][ns]);
        }
        if (more) {
            __syncthreads();
            *(uint4*)&Xs[xr][xc]       = xa;
            *(uint4*)&Xs[xr][xc + 8]   = xb;
            *(uint4*)&Ws[wr0][wc0]     = wv0a;
            *(uint4*)&Ws[wr0][wc0 + 8] = wv0b;
            *(uint4*)&Ws[wr1][wc1]     = wv1a;
            *(uint4*)&Ws[wr1][wc1 + 8] = wv1b;
            __syncthreads();
        }
    }
    __syncthreads();   // all compute reads done before smem reuse

    // ---- epilogue: through LDS, vectorized global stores ----
    float b1c[2], b2c[2], b3c[2];
    #pragma unroll
    for (int ns = 0; ns < 2; ++ns) {
        const int gcol = n0 + wave * 32 + ns * 16 + l16;
        if (mode == 0) { b1c[ns] = bq[gcol]; b2c[ns] = ub[gcol]; b3c[ns] = vbias[gcol]; }
        else if (mode == 1) { b1c[ns] = bk[gcol]; }
        else if (mode == 2) { b1c[ns] = bv[gcol]; }
        else b1c[ns] = 0.f;
    }

    const int npass = (mode == 0) ? 2 : 1;
    for (int pass = 0; pass < npass; ++pass) {
        // fill
        #pragma unroll
        for (int ms = 0; ms < 4; ++ms)
        #pragma unroll
        for (int ns = 0; ns < 2; ++ns)
        #pragma unroll
        for (int r = 0; r < 4; ++r) {
            const int lrow = ms * 16 + quad * 4 + r;
            const int lcol = wave * 32 + ns * 16 + l16;
            float v = acc[ms][ns][r];
            if (mode == 0) v += b1c[ns] + (pass == 0 ? b2c[ns] : b3c[ns]);
            else if (mode != 3) v += b1c[ns];
            if (mode == 2) EsT[lcol][lrow] = f2bf(v);
            else           Es[lrow][lcol]  = f2bf(v);
        }
        __syncthreads();
        // store
        if (mode == 2) {
            const int b = m0 >> 10;
            #pragma unroll
            for (int i = 0; i < 4; ++i) {
                int u = tid + 256 * i;
                int cl = u >> 3, off8 = (u & 7) * 8;
                uint4 d = *(const uint4*)&EsT[cl][off8];
                const int gcol = n0 + cl;
                ushort_t* dst = vtb + (((size_t)(b * HH + (gcol >> 6))) * CC + (gcol & 63)) * SS
                                + (m0 & 1023) + off8;
                *(uint4*)dst = d;
            }
        } else {
            #pragma unroll
            for (int i = 0; i < 4; ++i) {
                int u = tid + 256 * i;
                int seg = u >> 3, off8 = (u & 7) * 8;
                int sl = seg >> 1, hsel = seg & 1;
                int lc = hsel * 64 + off8;
                uint4 d = *(const uint4*)&Es[sl][lc];
                const int grow = m0 + sl;
                const int gcol = n0 + lc;
                if (mode == 3) {
                    if (grow < PP) {
                        ushort_t* dst = pbuf + ((size_t)(gcol >> 6) * PP + grow) * CC + (gcol & 63);
                        *(uint4*)dst = d;
                    }
                } else {
                    size_t idx = (((size_t)(grow >> 10) * HH + (gcol >> 6)) * SS + (grow & 1023)) * CC + (gcol & 63);
                    ushort_t* dst = (mode == 1) ? (kbuf + idx)
                                  : (pass == 0 ? (qu + idx) : (qvo + idx));
                    *(uint4*)dst = d;
                }
            }
        }
        if (pass + 1 < npass) __syncthreads();
    }
}

// ---------------------------------------------------------------------------
// Out-projection: bf16 X @ WtO^T + bout -> fp32. 64x128 tiles, 512 blocks,
// XCD swizzle, VGPR-prefetch double-buffering.
// ---------------------------------------------------------------------------
__global__ __launch_bounds__(256) void outproj_kernel(
    const ushort_t* __restrict__ X, const ushort_t* __restrict__ W,
    const float* __restrict__ b1, float* __restrict__ Yf)
{
    __shared__ __align__(16) ushort_t smem[64 * 72 + 128 * 72];
    ushort_t (*Xs)[72] = (ushort_t(*)[72])smem;
    ushort_t (*Ws)[72] = (ushort_t(*)[72])(smem + 64 * 72);

    const int tid = threadIdx.x;
    const int wave = tid >> 6, lane = tid & 63, quad = lane >> 4, l16 = lane & 15;
    const int bid = blockIdx.x;
    const int nt = (bid >> 3) & 3;
    const int mtl = (bid & 7) + 8 * (bid >> 5);
    const int n0 = nt * 128, m0 = mtl * 64;

    f32x4 acc[4][2];
    #pragma unroll
    for (int i = 0; i < 4; ++i)
        #pragma unroll
        for (int j = 0; j < 2; ++j) acc[i][j] = (f32x4){0.f, 0.f, 0.f, 0.f};

    const int xr = tid >> 2, xc = (tid & 3) * 16;
    const int wr0 = tid >> 2, wc0 = (tid & 3) * 16;
    const int wr1 = (tid + 256) >> 2, wc1 = wc0;

    {
        const ushort_t* xp = X + (size_t)(m0 + xr) * 512 + xc;
        *(uint4*)&Xs[xr][xc]     = *(const uint4*)xp;
        *(uint4*)&Xs[xr][xc + 8] = *(const uint4*)(xp + 8);
        const ushort_t* wp0 = W + (size_t)(n0 + wr0) * 512 + wc0;
        const ushort_t* wp1 = W + (size_t)(n0 + wr1) * 512 + wc1;
        *(uint4*)&Ws[wr0][wc0]     = *(const uint4*)wp0;
        *(uint4*)&Ws[wr0][wc0 + 8] = *(const uint4*)(wp0 + 8);
        *(uint4*)&Ws[wr1][wc1]     = *(const uint4*)wp1;
        *(uint4*)&Ws[wr1][wc1 + 8] = *(const uint4*)(wp1 + 8);
    }
    __syncthreads();

    for (int k0 = 0; k0 < 512; k0 += 64) {
        const bool more = (k0 + 64) < 512;
        uint4 xa, xb, wv0a, wv0b, wv1a, wv1b;
        if (more) {
            const ushort_t* xp = X + (size_t)(m0 + xr) * 512 + k0 + 64 + xc;
            xa = *(const uint4*)xp;
            xb = *(const uint4*)(xp + 8);
            const ushort_t* wp0 = W + (size_t)(n0 + wr0) * 512 + k0 + 64 + wc0;
            const ushort_t* wp1 = W + (size_t)(n0 + wr1) * 512 + k0 + 64 + wc1;
            wv0a = *(const uint4*)wp0; wv0b = *(const uint4*)(wp0 + 8);
            wv1a = *(const uint4*)wp1; wv1b = *(const uint4*)(wp1 + 8);
        }
        #pragma unroll
        for (int kk = 0; kk < 2; ++kk) {
            short8 av[4], bv4[2];
            #pragma unroll
            for (int ms = 0; ms < 4; ++ms)
                av[ms] = *(const short8*)&Xs[ms * 16 + l16][kk * 32 + quad * 8];
            #pragma unroll
            for (int ns = 0; ns < 2; ++ns)
                bv4[ns] = *(const short8*)&Ws[wave * 32 + ns * 16 + l16][kk * 32 + quad * 8];
            #pragma unroll
            for (int ms = 0; ms < 4; ++ms)
                #pragma unroll
                for (int ns = 0; ns < 2; ++ns)
                    acc[ms][ns] = MFMA(av[ms], bv4[ns], acc[ms][ns]);
        }
        if (more) {
            __syncthreads();
            *(uint4*)&Xs[xr][xc]       = xa;
            *(uint4*)&Xs[xr][xc + 8]   = xb;
            *(uint4*)&Ws[wr0][wc0]     = wv0a;
            *(uint4*)&Ws[wr0][wc0 + 8] = wv0b;
            *(uint4*)&Ws[wr1][wc1]     = wv1a;
            *(uint4*)&Ws[wr1][wc1 + 8] = wv1b;
            __syncthreads();
        }
    }

    #pragma unroll
    for (int ms = 0; ms < 4; ++ms)
    #pragma unroll
    for (int ns = 0; ns < 2; ++ns)
    #pragma unroll
    for (int r = 0; r < 4; ++r) {
        const int row = m0 + ms * 16 + quad * 4 + r;
        const int col = n0 + wave * 32 + ns * 16 + l16;
        Yf[(size_t)row * 512 + col] = acc[ms][ns][r] + b1[col];
    }
}

// ---------------------------------------------------------------------------
// Fused rel-pos flash attention, v12 = v11 + exp2-folded softmax.
// v11 post-mortem decoded the conflict counter: 6.82M = 26 b128 ops x 4
// structural cycles/iter (invariant under bpermute removal) — the LDS pipe
// is at its per-op floor everywhere. Last reducible term: the softmax VALU
// chain. __expf((s)*0.125-40) = mul+add+mul(log2e)+v_exp; folded to
// exp2f(fma(s, 0.125*log2e, -40*log2e)) = fma+v_exp — 32 fewer VALU ops
// per wave-iter on the serial chain. ~1 ulp score-level numeric shift
// (different rounding association), well inside the 2.3x absmax margin.
// If null: attn is at its structural floor (all LDS terms verified at
// hardware minimum for this decomposition; occupancy-capped at 16 waves/CU).
// Tripwires: absmax <= 0.0098, conflicts 6815744 (unchanged), WRITE 8192 KB.
// ---------------------------------------------------------------------------
__global__ __launch_bounds__(512, 4) void attn_kernel(
    const ushort_t* __restrict__ qu_g, const ushort_t* __restrict__ qv_g,
    const ushort_t* __restrict__ kb, const ushort_t* __restrict__ vt_g,
    const ushort_t* __restrict__ pbf, const unsigned char* __restrict__ mask,
    ushort_t* __restrict__ xg)
{
    const int bh = blockIdx.x;            // b*8 + h
    const int s0 = blockIdx.y * 128;
    const int b = bh >> 3, h = bh & 7;
    const int tid = threadIdx.x;
    const int wave = tid >> 6, lane = tid & 63, quad = lane >> 4, l16 = lane & 15;

    __shared__ __align__(16) ushort_t Ks[64][72];
    __shared__ __align__(16) ushort_t Vts[64][72];
    __shared__ __align__(16) ushort_t Pb[256][72];
    __shared__ __align__(16) ushort_t Pscr[8][16][76];   // stride 76: conflict-free P writes

    // Q fragments (A-operand, m = lane&15), loaded once
    const size_t qoff = ((size_t)bh * SS + s0 + wave * 16 + l16) * CC;
    short8 quA[2], qvA[2];
    quA[0] = *(const short8*)(qu_g + qoff + quad * 8);
    quA[1] = *(const short8*)(qu_g + qoff + 32 + quad * 8);
    qvA[0] = *(const short8*)(qv_g + qoff + quad * 8);
    qvA[1] = *(const short8*)(qv_g + qoff + 32 + quad * 8);

    f32x4 O[4];
    #pragma unroll
    for (int i = 0; i < 4; ++i) O[i] = (f32x4){0.f, 0.f, 0.f, 0.f};
    float lsum[4] = {0.f, 0.f, 0.f, 0.f};

    const ushort_t* kbase  = kb   + ((size_t)bh << 10) * CC;   // [t][c]
    const ushort_t* vtbase = vt_g + ((size_t)bh << 6) * SS;    // [c][s]
    const ushort_t* pbase  = pbf  + (size_t)h * PP * CC;       // [u][c]
    const unsigned char* mbase = mask + b * SS;

    const int R0base = 896 - s0;              // block band window start at t0=0
    const int uwread = 1008 - s0 - wave * 16; // +t0+us*16+l16 = global p row

    // exp(x*0.125 - 40) == exp2(x*C1 + C0)
    const float C1 = 0.125f * 1.4426950408889634f;   // 0.18033688
    const float C0 = -40.f  * 1.4426950408889634f;   // -57.70780163

    // ---- initial staging: K(t0=0), Vt(t0=0), 192-row p band ----
    {
        const int r = tid >> 3, cc = (tid & 7) * 8;
        *(uint4*)&Ks[r][cc]  = *(const uint4*)(kbase + (size_t)r * CC + cc);
        *(uint4*)&Vts[r][cc] = *(const uint4*)(vtbase + (size_t)r * SS + cc);
        #pragma unroll
        for (int i = 0; i < 3; ++i) {
            int u = tid + 512 * i; int rr = u >> 3; int c2 = (u & 7) * 8;
            int gr = R0base + rr;
            int g = gr; if (g < 0) g = 0; if (g > PP - 1) g = PP - 1;
            *(uint4*)&Pb[gr & 255][c2] = *(const uint4*)(pbase + (size_t)g * CC + c2);
        }
    }
    __syncthreads();

    for (int t0 = 0; t0 < SS; t0 += 64) {
        const bool more = (t0 + 64) < SS;
        // ---- prefetch next tile to VGPRs ----
        uint4 kp, vp, pp;
        const int r = tid >> 3, cc = (tid & 7) * 8;
        if (more) {
            kp = *(const uint4*)(kbase + (size_t)(t0 + 64 + r) * CC + cc);
            vp = *(const uint4*)(vtbase + (size_t)r * SS + t0 + 64 + cc);
            int g = R0base + t0 + 192 + r;
            if (g > PP - 1) g = PP - 1;
            pp = *(const uint4*)(pbase + (size_t)g * CC + cc);
        }

        // ---- AC = q_u . K^T ----
        __builtin_amdgcn_s_setprio(1);
        f32x4 ac[4];
        #pragma unroll
        for (int ns = 0; ns < 4; ++ns) {
            ac[ns] = (f32x4){0.f, 0.f, 0.f, 0.f};
            #pragma unroll
            for (int kk = 0; kk < 2; ++kk) {
                short8 kf = *(const short8*)&Ks[ns * 16 + l16][kk * 32 + quad * 8];
                ac[ns] = MFMA(quA[kk], kf, ac[ns]);
            }
        }
        // ---- band = q_v . p_band^T (wave-local 16 x 80) ----
        f32x4 bd[5];
        #pragma unroll
        for (int us = 0; us < 5; ++us) {
            bd[us] = (f32x4){0.f, 0.f, 0.f, 0.f};
            #pragma unroll
            for (int kk = 0; kk < 2; ++kk) {
                short8 pf = *(const short8*)&Pb[(uwread + t0 + us * 16 + l16) & 255][kk * 32 + quad * 8];
                bd[us] = MFMA(qvA[kk], pf, bd[us]);
            }
        }
        __builtin_amdgcn_s_setprio(0);

        // ---- shift: select-before-shuffle (4 bpermutes/rr) + exp2-folded
        //      softmax + mask; accumulate lsum ----
        bool mk[4];
        #pragma unroll
        for (int ns = 0; ns < 4; ++ns) mk[ns] = mbase[t0 + ns * 16 + l16] != 0;

        float pvv[4][4];
        #pragma unroll
        for (int rr = 0; rr < 4; ++rr) {
            const int sl = quad * 4 + rr;
            const int srcl = quad * 16 + ((l16 + 15 - sl) & 15);
            // This lane (as source) feeds dest l16d = (l16+sl+1)&15, whose
            // use_hi = l16d > sl. Pre-select so one shuffle serves each ns.
            const bool hi_src = (((l16 + sl + 1) & 15) > sl);
            float pre0 = hi_src ? bd[1][rr] : bd[0][rr];
            float pre1 = hi_src ? bd[2][rr] : bd[1][rr];
            float pre2 = hi_src ? bd[3][rr] : bd[2][rr];
            float pre3 = hi_src ? bd[4][rr] : bd[3][rr];
            float b0 = __shfl(pre0, srcl, 64);
            float b1 = __shfl(pre1, srcl, 64);
            float b2 = __shfl(pre2, srcl, 64);
            float b3 = __shfl(pre3, srcl, 64);
            float p0 = exp2f(fmaf(ac[0][rr] + b0, C1, C0));
            float p1 = exp2f(fmaf(ac[1][rr] + b1, C1, C0));
            float p2 = exp2f(fmaf(ac[2][rr] + b2, C1, C0));
            float p3 = exp2f(fmaf(ac[3][rr] + b3, C1, C0));
            p0 = mk[0] ? 0.f : p0;
            p1 = mk[1] ? 0.f : p1;
            p2 = mk[2] ? 0.f : p2;
            p3 = mk[3] ? 0.f : p3;
            pvv[0][rr] = p0; pvv[1][rr] = p1; pvv[2][rr] = p2; pvv[3][rr] = p3;
            lsum[rr] += p0; lsum[rr] += p1; lsum[rr] += p2; lsum[rr] += p3;
        }

        // ---- P: C/D layout -> A layout via wave-private LDS (stride 76) ----
        #pragma unroll
        for (int ns = 0; ns < 4; ++ns)
            #pragma unroll
            for (int rr = 0; rr < 4; ++rr)
                Pscr[wave][quad * 4 + rr][ns * 16 + l16] = f2bf(pvv[ns][rr]);
        union U8 { uint2 d[2]; short8 v; };
        U8 u0, u1;
        u0.d[0] = *(const uint2*)&Pscr[wave][l16][quad * 8];
        u0.d[1] = *(const uint2*)&Pscr[wave][l16][quad * 8 + 4];
        u1.d[0] = *(const uint2*)&Pscr[wave][l16][32 + quad * 8];
        u1.d[1] = *(const uint2*)&Pscr[wave][l16][32 + quad * 8 + 4];
        short8 pA0 = u0.v;
        short8 pA1 = u1.v;

        // ---- O += P . V ----
        __builtin_amdgcn_s_setprio(1);
        #pragma unroll
        for (int ns = 0; ns < 4; ++ns) {
            short8 v0 = *(const short8*)&Vts[ns * 16 + l16][quad * 8];
            short8 v1 = *(const short8*)&Vts[ns * 16 + l16][32 + quad * 8];
            O[ns] = MFMA(pA0, v0, O[ns]);
            O[ns] = MFMA(pA1, v1, O[ns]);
        }
        __builtin_amdgcn_s_setprio(0);

        if (more) {
            __syncthreads();   // all waves done reading Ks/Vts/Pb
            *(uint4*)&Ks[r][cc]  = kp;
            *(uint4*)&Vts[r][cc] = vp;
            *(uint4*)&Pb[(R0base + t0 + 192 + r) & 255][cc] = pp;
            __syncthreads();
        }
    }

    // ---- finalize: reduce lsum over 16 lanes, O /= l, transpose via Pscr,
    //      coalesced dwordx4 stores (reads via uint2: rows 8B-aligned) ----
    #pragma unroll
    for (int rr = 0; rr < 4; ++rr) {
        float s = lsum[rr];
        s += __shfl_xor(s, 1, 64); s += __shfl_xor(s, 2, 64);
        s += __shfl_xor(s, 4, 64); s += __shfl_xor(s, 8, 64);
        const float inv = 1.0f / s;
        #pragma unroll
        for (int ns = 0; ns < 4; ++ns)
            Pscr[wave][quad * 4 + rr][ns * 16 + l16] = f2bf(O[ns][rr] * inv);
    }
    {
        union U16 { uint2 d[4]; uint4 q[2]; };
        U16 uf;
        const ushort_t* src = &Pscr[wave][lane >> 2][(lane & 3) * 16];
        uf.d[0] = *(const uint2*)(src);
        uf.d[1] = *(const uint2*)(src + 4);
        uf.d[2] = *(const uint2*)(src + 8);
        uf.d[3] = *(const uint2*)(src + 12);
        const int srow = s0 + wave * 16 + (lane >> 2);
        ushort_t* dst = xg + ((size_t)b * SS + srow) * DD + h * CC + (lane & 3) * 16;
        *(uint4*)dst = uf.q[0];
        *(uint4*)(dst + 8) = uf.q[1];
    }
}

// ---------------------------------------------------------------------------
extern "C" void kernel_launch(void* const* d_in, const int* in_sizes, int n_in,
                              void* d_out, int out_size, void* d_ws, size_t ws_size,
                              hipStream_t stream)
{
    (void)in_sizes; (void)n_in; (void)out_size; (void)ws_size;

    const float* query = (const float*)d_in[0];
    const float* key_  = (const float*)d_in[1];
    const float* value = (const float*)d_in[2];
    const float* pos   = (const float*)d_in[3];
    const unsigned char* mask = (const unsigned char*)d_in[4];
    const float* Wq   = (const float*)d_in[5];
    const float* bq   = (const float*)d_in[6];
    const float* Wk   = (const float*)d_in[7];
    const float* bk   = (const float*)d_in[8];
    const float* Wv   = (const float*)d_in[9];
    const float* bv   = (const float*)d_in[10];
    const float* Wpos = (const float*)d_in[11];
    const float* Wout = (const float*)d_in[12];
    const float* bout = (const float*)d_in[13];
    const float* ub   = (const float*)d_in[14];
    const float* vb   = (const float*)d_in[15];

    const size_t NBS = (size_t)BB * SS * DD;   // 4194304
    const size_t NP  = (size_t)PP * DD;        // 1048064
    const size_t NW  = (size_t)DD * DD;        // 262144

    ushort_t* wt   = (ushort_t*)d_ws;          // 5 transposed weights
    ushort_t* qu   = wt + 5 * NW;
    ushort_t* qv   = qu + NBS;
    ushort_t* kbuf = qv + NBS;
    ushort_t* vtb  = kbuf + NBS;               // V^T [bh][c][s]
    ushort_t* pbuf = vtb + NBS;                // [h][u][c]
    ushort_t* xg   = pbuf + NP;

    ushort_t* WtO = wt + 4 * NW;

    wtrans_kernel<<<dim3(320), dim3(256), 0, stream>>>(Wq, Wk, Wv, Wpos, Wout, wt);

    qkvpos_kernel<<<dim3(1664), dim3(256), 0, stream>>>(
        query, key_, value, pos, wt, bq, bk, bv, ub, vb,
        qu, qv, kbuf, vtb, pbuf);

    attn_kernel<<<dim3(64, 8), dim3(512), 0, stream>>>(qu, qv, kbuf, vtb, pbuf, mask, xg);

    outproj_kernel<<<dim3(512), dim3(256), 0, stream>>>(xg, WtO, bout, (float*)d_out);
}

// Round 12
// 215.879 us; speedup vs baseline: 1.0276x; 1.0276x over previous
//
#include <hip/hip_runtime.h>
#include <math.h>

typedef unsigned short ushort_t;
typedef __attribute__((ext_vector_type(8))) short short8;
typedef __attribute__((ext_vector_type(4))) float f32x4;

#define MFMA(a,b,c) __builtin_amdgcn_mfma_f32_16x16x32_bf16((a),(b),(c),0,0,0)

// Problem constants
#define BB 8
#define SS 1024
#define DD 512
#define HH 8
#define CC 64
#define PP 2047   // 2S-1

// Packed fp32x2 -> bf16x2 (RNE), single HW instruction. Bit-identical to the
// RNE bit-twiddle for normal inputs (validated: v5 staging swap, absmax same).
static __device__ __forceinline__ unsigned pack2(float a, float b) {
    unsigned r;
    asm("v_cvt_pk_bf16_f32 %0, %1, %2" : "=v"(r) : "v"(a), "v"(b));
    return r;
}
// Scalar fp32 -> bf16 (RNE) via the same instruction (1 VALU vs ~4).
static __device__ __forceinline__ ushort_t f2bf(float f) {
    unsigned r;
    asm("v_cvt_pk_bf16_f32 %0, %1, %2" : "=v"(r) : "v"(f), "v"(f));
    return (ushort_t)r;
}
// Raw v_exp_f32 (2^x) — the HW op __expf uses internally, without libm
// exp2f's range-handling expansion (v12 lesson: exp2f cost +8pts VALUBusy).
static __device__ __forceinline__ float exp2_raw(float x) {
    float r;
    asm("v_exp_f32 %0, %1" : "=v"(r) : "v"(x));
    return r;
}

// ---------------------------------------------------------------------------
// Weight transpose+cast: W[k][n] fp32 -> Wt[n][k] bf16, 5 weights.
// ---------------------------------------------------------------------------
__global__ __launch_bounds__(256) void wtrans_kernel(
    const float* __restrict__ Wq, const float* __restrict__ Wk,
    const float* __restrict__ Wv, const float* __restrict__ Wp,
    const float* __restrict__ Wo, ushort_t* __restrict__ wt)
{
    __shared__ float T[64][65];
    const int bid = blockIdx.x, tid = threadIdx.x;
    const int wi   = bid >> 6;
    const int tile = bid & 63;
    const float* Wsrc = (wi == 0) ? Wq : (wi == 1) ? Wk : (wi == 2) ? Wv
                      : (wi == 3) ? Wp : Wo;
    ushort_t* Wdst = wt + (size_t)wi * 262144;
    const int tk0 = (tile >> 3) * 64, tn0 = (tile & 7) * 64;
    const int r = tid >> 2, c4 = (tid & 3) * 16;
    #pragma unroll
    for (int rep = 0; rep < 4; ++rep) {
        float4 f = *(const float4*)(Wsrc + (size_t)(tk0 + r) * 512 + tn0 + c4 + rep * 4);
        T[r][c4 + rep * 4 + 0] = f.x; T[r][c4 + rep * 4 + 1] = f.y;
        T[r][c4 + rep * 4 + 2] = f.z; T[r][c4 + rep * 4 + 3] = f.w;
    }
    __syncthreads();
    #pragma unroll
    for (int rep = 0; rep < 4; ++rep) {
        uint2 u;
        u.x = pack2(T[c4 + rep * 4 + 0][r], T[c4 + rep * 4 + 1][r]);
        u.y = pack2(T[c4 + rep * 4 + 2][r], T[c4 + rep * 4 + 3][r]);
        *(uint2*)(Wdst + (size_t)(tn0 + r) * 512 + tk0 + c4 + rep * 4) = u;
    }
}

// ---------------------------------------------------------------------------
// Fused Q/K/V/pos projection. 64(m)x128(n) tiles, 1664 blocks, XCD swizzle.
// VGPR-prefetch double-buffering. 4 waves, each m64 x n32 (4x2 frags). BK=64.
// fp32->bf16 cast via v_cvt_pk_bf16_f32.
// ---------------------------------------------------------------------------
__global__ __launch_bounds__(256) void qkvpos_kernel(
    const float* __restrict__ Xq, const float* __restrict__ Xk,
    const float* __restrict__ Xv, const float* __restrict__ Xp,
    const ushort_t* __restrict__ wt,
    const float* __restrict__ bq, const float* __restrict__ bk,
    const float* __restrict__ bv,
    const float* __restrict__ ub, const float* __restrict__ vbias,
    ushort_t* __restrict__ qu, ushort_t* __restrict__ qvo,
    ushort_t* __restrict__ kbuf, ushort_t* __restrict__ vtb,
    ushort_t* __restrict__ pbuf)
{
    __shared__ __align__(16) ushort_t smem[64 * 72 + 128 * 72];
    ushort_t (*Xs)[72] = (ushort_t(*)[72])smem;            // [64][72]
    ushort_t (*Ws)[72] = (ushort_t(*)[72])(smem + 64 * 72);// [128][72]
    ushort_t (*Es)[136] = (ushort_t(*)[136])smem;          // epilogue [64][136]
    ushort_t (*EsT)[72] = (ushort_t(*)[72])smem;           // epilogue T [128][72]

    const int tid = threadIdx.x;
    const int wave = tid >> 6, lane = tid & 63, quad = lane >> 4, l16 = lane & 15;
    const int bid = blockIdx.x;
    const int nt = (bid >> 3) & 3;
    const int mt = (bid & 7) + 8 * (bid >> 5);
    const int n0 = nt * 128;
    int mode, mtl;
    if (mt < 128)      { mode = 0; mtl = mt; }
    else if (mt < 256) { mode = 1; mtl = mt - 128; }
    else if (mt < 384) { mode = 2; mtl = mt - 256; }
    else               { mode = 3; mtl = mt - 384; }
    const int m0 = mtl * 64;
    const float* X = (mode == 0) ? Xq : (mode == 1) ? Xk : (mode == 2) ? Xv : Xp;
    const ushort_t* W = wt + (size_t)mode * 262144;

    f32x4 acc[4][2];
    #pragma unroll
    for (int i = 0; i < 4; ++i)
        #pragma unroll
        for (int j = 0; j < 2; ++j) acc[i][j] = (f32x4){0.f, 0.f, 0.f, 0.f};

    const int xr = tid >> 2, xc = (tid & 3) * 16;   // X stage: 4 thr/row
    int xrow = m0 + xr;
    if (mode == 3 && xrow > PP - 1) xrow = PP - 1;
    const int wr0 = tid >> 2, wc0 = (tid & 3) * 16;          // W i=0
    const int wr1 = (tid + 256) >> 2, wc1 = wc0;             // W i=1

    // ---- initial stage k0=0 ----
    {
        const float* xp = X + (size_t)xrow * 512 + xc;
        float4 f0 = *(const float4*)xp;
        float4 f1 = *(const float4*)(xp + 4);
        float4 f2 = *(const float4*)(xp + 8);
        float4 f3 = *(const float4*)(xp + 12);
        uint4 a, bpk;
        a.x = pack2(f0.x, f0.y); a.y = pack2(f0.z, f0.w);
        a.z = pack2(f1.x, f1.y); a.w = pack2(f1.z, f1.w);
        bpk.x = pack2(f2.x, f2.y); bpk.y = pack2(f2.z, f2.w);
        bpk.z = pack2(f3.x, f3.y); bpk.w = pack2(f3.z, f3.w);
        *(uint4*)&Xs[xr][xc] = a;
        *(uint4*)&Xs[xr][xc + 8] = bpk;
        const ushort_t* wp0 = W + (size_t)(n0 + wr0) * 512 + wc0;
        const ushort_t* wp1 = W + (size_t)(n0 + wr1) * 512 + wc1;
        *(uint4*)&Ws[wr0][wc0]     = *(const uint4*)wp0;
        *(uint4*)&Ws[wr0][wc0 + 8] = *(const uint4*)(wp0 + 8);
        *(uint4*)&Ws[wr1][wc1]     = *(const uint4*)wp1;
        *(uint4*)&Ws[wr1][wc1 + 8] = *(const uint4*)(wp1 + 8);
    }
    __syncthreads();

    for (int k0 = 0; k0 < 512; k0 += 64) {
        const bool more = (k0 + 64) < 512;
        // ---- prefetch next k-tile into VGPRs (overlaps compute below) ----
        uint4 xa, xb, wv0a, wv0b, wv1a, wv1b;
        if (more) {
            const float* xp = X + (size_t)xrow * 512 + k0 + 64 + xc;
            float4 f0 = *(const float4*)xp;
            float4 f1 = *(const float4*)(xp + 4);
            float4 f2 = *(const float4*)(xp + 8);
            float4 f3 = *(const float4*)(xp + 12);
            xa.x = pack2(f0.x, f0.y); xa.y = pack2(f0.z, f0.w);
            xa.z = pack2(f1.x, f1.y); xa.w = pack2(f1.z, f1.w);
            xb.x = pack2(f2.x, f2.y); xb.y = pack2(f2.z, f2.w);
            xb.z = pack2(f3.x, f3.y); xb.w = pack2(f3.z, f3.w);
            const ushort_t* wp0 = W + (size_t)(n0 + wr0) * 512 + k0 + 64 + wc0;
            const ushort_t* wp1 = W + (size_t)(n0 + wr1) * 512 + k0 + 64 + wc1;
            wv0a = *(const uint4*)wp0; wv0b = *(const uint4*)(wp0 + 8);
            wv1a = *(const uint4*)wp1; wv1b = *(const uint4*)(wp1 + 8);
        }
        // ---- compute on current LDS tile ----
        #pragma unroll
        for (int kk = 0; kk < 2; ++kk) {
            short8 av[4], bv4[2];
            #pragma unroll
            for (int ms = 0; ms < 4; ++ms)
                av[ms] = *(const short8*)&Xs[ms * 16 + l16][kk * 32 + quad * 8];
            #pragma unroll
            for (int ns = 0; ns < 2; ++ns)
                bv4[ns] = *(const short8*)&Ws[wave * 32 + ns * 16 + l16][kk * 32 + quad * 8];
            #pragma unroll
            for (int ms = 0; ms < 4; ++ms)
                #pragma unroll
                for (int ns = 0; ns < 2; ++ns)
                    acc[ms][ns] = MFMA(av[ms], bv4[ns], acc[ms][ns]);
        }
        if (more) {
            __syncthreads();
            *(uint4*)&Xs[xr][xc]       = xa;
            *(uint4*)&Xs[xr][xc + 8]   = xb;
            *(uint4*)&Ws[wr0][wc0]     = wv0a;
            *(uint4*)&Ws[wr0][wc0 + 8] = wv0b;
            *(uint4*)&Ws[wr1][wc1]     = wv1a;
            *(uint4*)&Ws[wr1][wc1 + 8] = wv1b;
            __syncthreads();
        }
    }
    __syncthreads();   // all compute reads done before smem reuse

    // ---- epilogue: through LDS, vectorized global stores ----
    float b1c[2], b2c[2], b3c[2];
    #pragma unroll
    for (int ns = 0; ns < 2; ++ns) {
        const int gcol = n0 + wave * 32 + ns * 16 + l16;
        if (mode == 0) { b1c[ns] = bq[gcol]; b2c[ns] = ub[gcol]; b3c[ns] = vbias[gcol]; }
        else if (mode == 1) { b1c[ns] = bk[gcol]; }
        else if (mode == 2) { b1c[ns] = bv[gcol]; }
        else b1c[ns] = 0.f;
    }

    const int npass = (mode == 0) ? 2 : 1;
    for (int pass = 0; pass < npass; ++pass) {
        // fill
        #pragma unroll
        for (int ms = 0; ms < 4; ++ms)
        #pragma unroll
        for (int ns = 0; ns < 2; ++ns)
        #pragma unroll
        for (int r = 0; r < 4; ++r) {
            const int lrow = ms * 16 + quad * 4 + r;
            const int lcol = wave * 32 + ns * 16 + l16;
            float v = acc[ms][ns][r];
            if (mode == 0) v += b1c[ns] + (pass == 0 ? b2c[ns] : b3c[ns]);
            else if (mode != 3) v += b1c[ns];
            if (mode == 2) EsT[lcol][lrow] = f2bf(v);
            else           Es[lrow][lcol]  = f2bf(v);
        }
        __syncthreads();
        // store
        if (mode == 2) {
            const int b = m0 >> 10;
            #pragma unroll
            for (int i = 0; i < 4; ++i) {
                int u = tid + 256 * i;
                int cl = u >> 3, off8 = (u & 7) * 8;
                uint4 d = *(const uint4*)&EsT[cl][off8];
                const int gcol = n0 + cl;
                ushort_t* dst = vtb + (((size_t)(b * HH + (gcol >> 6))) * CC + (gcol & 63)) * SS
                                + (m0 & 1023) + off8;
                *(uint4*)dst = d;
            }
        } else {
            #pragma unroll
            for (int i = 0; i < 4; ++i) {
                int u = tid + 256 * i;
                int seg = u >> 3, off8 = (u & 7) * 8;
                int sl = seg >> 1, hsel = seg & 1;
                int lc = hsel * 64 + off8;
                uint4 d = *(const uint4*)&Es[sl][lc];
                const int grow = m0 + sl;
                const int gcol = n0 + lc;
                if (mode == 3) {
                    if (grow < PP) {
                        ushort_t* dst = pbuf + ((size_t)(gcol >> 6) * PP + grow) * CC + (gcol & 63);
                        *(uint4*)dst = d;
                    }
                } else {
                    size_t idx = (((size_t)(grow >> 10) * HH + (gcol >> 6)) * SS + (grow & 1023)) * CC + (gcol & 63);
                    ushort_t* dst = (mode == 1) ? (kbuf + idx)
                                  : (pass == 0 ? (qu + idx) : (qvo + idx));
                    *(uint4*)dst = d;
                }
            }
        }
        if (pass + 1 < npass) __syncthreads();
    }
}

// ---------------------------------------------------------------------------
// Out-projection: bf16 X @ WtO^T + bout -> fp32. 64x128 tiles, 512 blocks,
// XCD swizzle, VGPR-prefetch double-buffering.
// ---------------------------------------------------------------------------
__global__ __launch_bounds__(256) void outproj_kernel(
    const ushort_t* __restrict__ X, const ushort_t* __restrict__ W,
    const float* __restrict__ b1, float* __restrict__ Yf)
{
    __shared__ __align__(16) ushort_t smem[64 * 72 + 128 * 72];
    ushort_t (*Xs)[72] = (ushort_t(*)[72])smem;
    ushort_t (*Ws)[72] = (ushort_t(*)[72])(smem + 64 * 72);

    const int tid = threadIdx.x;
    const int wave = tid >> 6, lane = tid & 63, quad = lane >> 4, l16 = lane & 15;
    const int bid = blockIdx.x;
    const int nt = (bid >> 3) & 3;
    const int mtl = (bid & 7) + 8 * (bid >> 5);
    const int n0 = nt * 128, m0 = mtl * 64;

    f32x4 acc[4][2];
    #pragma unroll
    for (int i = 0; i < 4; ++i)
        #pragma unroll
        for (int j = 0; j < 2; ++j) acc[i][j] = (f32x4){0.f, 0.f, 0.f, 0.f};

    const int xr = tid >> 2, xc = (tid & 3) * 16;
    const int wr0 = tid >> 2, wc0 = (tid & 3) * 16;
    const int wr1 = (tid + 256) >> 2, wc1 = wc0;

    {
        const ushort_t* xp = X + (size_t)(m0 + xr) * 512 + xc;
        *(uint4*)&Xs[xr][xc]     = *(const uint4*)xp;
        *(uint4*)&Xs[xr][xc + 8] = *(const uint4*)(xp + 8);
        const ushort_t* wp0 = W + (size_t)(n0 + wr0) * 512 + wc0;
        const ushort_t* wp1 = W + (size_t)(n0 + wr1) * 512 + wc1;
        *(uint4*)&Ws[wr0][wc0]     = *(const uint4*)wp0;
        *(uint4*)&Ws[wr0][wc0 + 8] = *(const uint4*)(wp0 + 8);
        *(uint4*)&Ws[wr1][wc1]     = *(const uint4*)wp1;
        *(uint4*)&Ws[wr1][wc1 + 8] = *(const uint4*)(wp1 + 8);
    }
    __syncthreads();

    for (int k0 = 0; k0 < 512; k0 += 64) {
        const bool more = (k0 + 64) < 512;
        uint4 xa, xb, wv0a, wv0b, wv1a, wv1b;
        if (more) {
            const ushort_t* xp = X + (size_t)(m0 + xr) * 512 + k0 + 64 + xc;
            xa = *(const uint4*)xp;
            xb = *(const uint4*)(xp + 8);
            const ushort_t* wp0 = W + (size_t)(n0 + wr0) * 512 + k0 + 64 + wc0;
            const ushort_t* wp1 = W + (size_t)(n0 + wr1) * 512 + k0 + 64 + wc1;
            wv0a = *(const uint4*)wp0; wv0b = *(const uint4*)(wp0 + 8);
            wv1a = *(const uint4*)wp1; wv1b = *(const uint4*)(wp1 + 8);
        }
        #pragma unroll
        for (int kk = 0; kk < 2; ++kk) {
            short8 av[4], bv4[2];
            #pragma unroll
            for (int ms = 0; ms < 4; ++ms)
                av[ms] = *(const short8*)&Xs[ms * 16 + l16][kk * 32 + quad * 8];
            #pragma unroll
            for (int ns = 0; ns < 2; ++ns)
                bv4[ns] = *(const short8*)&Ws[wave * 32 + ns * 16 + l16][kk * 32 + quad * 8];
            #pragma unroll
            for (int ms = 0; ms < 4; ++ms)
                #pragma unroll
                for (int ns = 0; ns < 2; ++ns)
                    acc[ms][ns] = MFMA(av[ms], bv4[ns], acc[ms][ns]);
        }
        if (more) {
            __syncthreads();
            *(uint4*)&Xs[xr][xc]       = xa;
            *(uint4*)&Xs[xr][xc + 8]   = xb;
            *(uint4*)&Ws[wr0][wc0]     = wv0a;
            *(uint4*)&Ws[wr0][wc0 + 8] = wv0b;
            *(uint4*)&Ws[wr1][wc1]     = wv1a;
            *(uint4*)&Ws[wr1][wc1 + 8] = wv1b;
            __syncthreads();
        }
    }

    #pragma unroll
    for (int ms = 0; ms < 4; ++ms)
    #pragma unroll
    for (int ns = 0; ns < 2; ++ns)
    #pragma unroll
    for (int r = 0; r < 4; ++r) {
        const int row = m0 + ms * 16 + quad * 4 + r;
        const int col = n0 + wave * 32 + ns * 16 + l16;
        Yf[(size_t)row * 512 + col] = acc[ms][ns][r] + b1[col];
    }
}

// ---------------------------------------------------------------------------
// Fused rel-pos flash attention, v13 = v11 + CORRECT exp folding.
// v12 post-mortem: exp2f() (libm) expands to a range-handling sequence
// (+8pts VALUBusy, 62.7->67.4 us) — it does NOT map to bare v_exp_f32.
// __expf = mul(log2e)+v_exp. v13 uses raw inline-asm v_exp_f32 with the
// argument folded to one fma: add -> fma(C1,C0) -> v_exp (3 ops vs v11's 5).
// exp2-of-fma numerics already validated by v12's PASS (absmax 0.0078125);
// args in [-101,-14] are normal-range for v_exp_f32.
// Everything else byte-identical to verified v11 (62.7 us).
// If null: attn is at its structural floor — declare plateau.
// Tripwires: absmax <= 0.018, conflicts 6815744, WRITE 8192 KB, VGPR <= 64.
// ---------------------------------------------------------------------------
__global__ __launch_bounds__(512, 4) void attn_kernel(
    const ushort_t* __restrict__ qu_g, const ushort_t* __restrict__ qv_g,
    const ushort_t* __restrict__ kb, const ushort_t* __restrict__ vt_g,
    const ushort_t* __restrict__ pbf, const unsigned char* __restrict__ mask,
    ushort_t* __restrict__ xg)
{
    const int bh = blockIdx.x;            // b*8 + h
    const int s0 = blockIdx.y * 128;
    const int b = bh >> 3, h = bh & 7;
    const int tid = threadIdx.x;
    const int wave = tid >> 6, lane = tid & 63, quad = lane >> 4, l16 = lane & 15;

    __shared__ __align__(16) ushort_t Ks[64][72];
    __shared__ __align__(16) ushort_t Vts[64][72];
    __shared__ __align__(16) ushort_t Pb[256][72];
    __shared__ __align__(16) ushort_t Pscr[8][16][76];   // stride 76: conflict-free P writes

    // Q fragments (A-operand, m = lane&15), loaded once
    const size_t qoff = ((size_t)bh * SS + s0 + wave * 16 + l16) * CC;
    short8 quA[2], qvA[2];
    quA[0] = *(const short8*)(qu_g + qoff + quad * 8);
    quA[1] = *(const short8*)(qu_g + qoff + 32 + quad * 8);
    qvA[0] = *(const short8*)(qv_g + qoff + quad * 8);
    qvA[1] = *(const short8*)(qv_g + qoff + 32 + quad * 8);

    f32x4 O[4];
    #pragma unroll
    for (int i = 0; i < 4; ++i) O[i] = (f32x4){0.f, 0.f, 0.f, 0.f};
    float lsum[4] = {0.f, 0.f, 0.f, 0.f};

    const ushort_t* kbase  = kb   + ((size_t)bh << 10) * CC;   // [t][c]
    const ushort_t* vtbase = vt_g + ((size_t)bh << 6) * SS;    // [c][s]
    const ushort_t* pbase  = pbf  + (size_t)h * PP * CC;       // [u][c]
    const unsigned char* mbase = mask + b * SS;

    const int R0base = 896 - s0;              // block band window start at t0=0
    const int uwread = 1008 - s0 - wave * 16; // +t0+us*16+l16 = global p row

    // exp(x*0.125 - 40) == 2^(x*C1 + C0)
    const float C1 = 0.125f * 1.4426950408889634f;   // 0.18033688
    const float C0 = -40.f  * 1.4426950408889634f;   // -57.70780163

    // ---- initial staging: K(t0=0), Vt(t0=0), 192-row p band ----
    {
        const int r = tid >> 3, cc = (tid & 7) * 8;
        *(uint4*)&Ks[r][cc]  = *(const uint4*)(kbase + (size_t)r * CC + cc);
        *(uint4*)&Vts[r][cc] = *(const uint4*)(vtbase + (size_t)r * SS + cc);
        #pragma unroll
        for (int i = 0; i < 3; ++i) {
            int u = tid + 512 * i; int rr = u >> 3; int c2 = (u & 7) * 8;
            int gr = R0base + rr;
            int g = gr; if (g < 0) g = 0; if (g > PP - 1) g = PP - 1;
            *(uint4*)&Pb[gr & 255][c2] = *(const uint4*)(pbase + (size_t)g * CC + c2);
        }
    }
    __syncthreads();

    for (int t0 = 0; t0 < SS; t0 += 64) {
        const bool more = (t0 + 64) < SS;
        // ---- prefetch next tile to VGPRs ----
        uint4 kp, vp, pp;
        const int r = tid >> 3, cc = (tid & 7) * 8;
        if (more) {
            kp = *(const uint4*)(kbase + (size_t)(t0 + 64 + r) * CC + cc);
            vp = *(const uint4*)(vtbase + (size_t)r * SS + t0 + 64 + cc);
            int g = R0base + t0 + 192 + r;
            if (g > PP - 1) g = PP - 1;
            pp = *(const uint4*)(pbase + (size_t)g * CC + cc);
        }

        // ---- AC = q_u . K^T ----
        __builtin_amdgcn_s_setprio(1);
        f32x4 ac[4];
        #pragma unroll
        for (int ns = 0; ns < 4; ++ns) {
            ac[ns] = (f32x4){0.f, 0.f, 0.f, 0.f};
            #pragma unroll
            for (int kk = 0; kk < 2; ++kk) {
                short8 kf = *(const short8*)&Ks[ns * 16 + l16][kk * 32 + quad * 8];
                ac[ns] = MFMA(quA[kk], kf, ac[ns]);
            }
        }
        // ---- band = q_v . p_band^T (wave-local 16 x 80) ----
        f32x4 bd[5];
        #pragma unroll
        for (int us = 0; us < 5; ++us) {
            bd[us] = (f32x4){0.f, 0.f, 0.f, 0.f};
            #pragma unroll
            for (int kk = 0; kk < 2; ++kk) {
                short8 pf = *(const short8*)&Pb[(uwread + t0 + us * 16 + l16) & 255][kk * 32 + quad * 8];
                bd[us] = MFMA(qvA[kk], pf, bd[us]);
            }
        }
        __builtin_amdgcn_s_setprio(0);

        // ---- shift: select-before-shuffle (4 bpermutes/rr) + fma+v_exp
        //      softmax + mask; accumulate lsum ----
        bool mk[4];
        #pragma unroll
        for (int ns = 0; ns < 4; ++ns) mk[ns] = mbase[t0 + ns * 16 + l16] != 0;

        float pvv[4][4];
        #pragma unroll
        for (int rr = 0; rr < 4; ++rr) {
            const int sl = quad * 4 + rr;
            const int srcl = quad * 16 + ((l16 + 15 - sl) & 15);
            // This lane (as source) feeds dest l16d = (l16+sl+1)&15, whose
            // use_hi = l16d > sl. Pre-select so one shuffle serves each ns.
            const bool hi_src = (((l16 + sl + 1) & 15) > sl);
            float pre0 = hi_src ? bd[1][rr] : bd[0][rr];
            float pre1 = hi_src ? bd[2][rr] : bd[1][rr];
            float pre2 = hi_src ? bd[3][rr] : bd[2][rr];
            float pre3 = hi_src ? bd[4][rr] : bd[3][rr];
            float b0 = __shfl(pre0, srcl, 64);
            float b1 = __shfl(pre1, srcl, 64);
            float b2 = __shfl(pre2, srcl, 64);
            float b3 = __shfl(pre3, srcl, 64);
            float p0 = exp2_raw(fmaf(ac[0][rr] + b0, C1, C0));
            float p1 = exp2_raw(fmaf(ac[1][rr] + b1, C1, C0));
            float p2 = exp2_raw(fmaf(ac[2][rr] + b2, C1, C0));
            float p3 = exp2_raw(fmaf(ac[3][rr] + b3, C1, C0));
            p0 = mk[0] ? 0.f : p0;
            p1 = mk[1] ? 0.f : p1;
            p2 = mk[2] ? 0.f : p2;
            p3 = mk[3] ? 0.f : p3;
            pvv[0][rr] = p0; pvv[1][rr] = p1; pvv[2][rr] = p2; pvv[3][rr] = p3;
            lsum[rr] += p0; lsum[rr] += p1; lsum[rr] += p2; lsum[rr] += p3;
        }

        // ---- P: C/D layout -> A layout via wave-private LDS (stride 76) ----
        #pragma unroll
        for (int ns = 0; ns < 4; ++ns)
            #pragma unroll
            for (int rr = 0; rr < 4; ++rr)
                Pscr[wave][quad * 4 + rr][ns * 16 + l16] = f2bf(pvv[ns][rr]);
        union U8 { uint2 d[2]; short8 v; };
        U8 u0, u1;
        u0.d[0] = *(const uint2*)&Pscr[wave][l16][quad * 8];
        u0.d[1] = *(const uint2*)&Pscr[wave][l16][quad * 8 + 4];
        u1.d[0] = *(const uint2*)&Pscr[wave][l16][32 + quad * 8];
        u1.d[1] = *(const uint2*)&Pscr[wave][l16][32 + quad * 8 + 4];
        short8 pA0 = u0.v;
        short8 pA1 = u1.v;

        // ---- O += P . V ----
        __builtin_amdgcn_s_setprio(1);
        #pragma unroll
        for (int ns = 0; ns < 4; ++ns) {
            short8 v0 = *(const short8*)&Vts[ns * 16 + l16][quad * 8];
            short8 v1 = *(const short8*)&Vts[ns * 16 + l16][32 + quad * 8];
            O[ns] = MFMA(pA0, v0, O[ns]);
            O[ns] = MFMA(pA1, v1, O[ns]);
        }
        __builtin_amdgcn_s_setprio(0);

        if (more) {
            __syncthreads();   // all waves done reading Ks/Vts/Pb
            *(uint4*)&Ks[r][cc]  = kp;
            *(uint4*)&Vts[r][cc] = vp;
            *(uint4*)&Pb[(R0base + t0 + 192 + r) & 255][cc] = pp;
            __syncthreads();
        }
    }

    // ---- finalize: reduce lsum over 16 lanes, O /= l, transpose via Pscr,
    //      coalesced dwordx4 stores (reads via uint2: rows 8B-aligned) ----
    #pragma unroll
    for (int rr = 0; rr < 4; ++rr) {
        float s = lsum[rr];
        s += __shfl_xor(s, 1, 64); s += __shfl_xor(s, 2, 64);
        s += __shfl_xor(s, 4, 64); s += __shfl_xor(s, 8, 64);
        const float inv = 1.0f / s;
        #pragma unroll
        for (int ns = 0; ns < 4; ++ns)
            Pscr[wave][quad * 4 + rr][ns * 16 + l16] = f2bf(O[ns][rr] * inv);
    }
    {
        union U16 { uint2 d[4]; uint4 q[2]; };
        U16 uf;
        const ushort_t* src = &Pscr[wave][lane >> 2][(lane & 3) * 16];
        uf.d[0] = *(const uint2*)(src);
        uf.d[1] = *(const uint2*)(src + 4);
        uf.d[2] = *(const uint2*)(src + 8);
        uf.d[3] = *(const uint2*)(src + 12);
        const int srow = s0 + wave * 16 + (lane >> 2);
        ushort_t* dst = xg + ((size_t)b * SS + srow) * DD + h * CC + (lane & 3) * 16;
        *(uint4*)dst = uf.q[0];
        *(uint4*)(dst + 8) = uf.q[1];
    }
}

// ---------------------------------------------------------------------------
extern "C" void kernel_launch(void* const* d_in, const int* in_sizes, int n_in,
                              void* d_out, int out_size, void* d_ws, size_t ws_size,
                              hipStream_t stream)
{
    (void)in_sizes; (void)n_in; (void)out_size; (void)ws_size;

    const float* query = (const float*)d_in[0];
    const float* key_  = (const float*)d_in[1];
    const float* value = (const float*)d_in[2];
    const float* pos   = (const float*)d_in[3];
    const unsigned char* mask = (const unsigned char*)d_in[4];
    const float* Wq   = (const float*)d_in[5];
    const float* bq   = (const float*)d_in[6];
    const float* Wk   = (const float*)d_in[7];
    const float* bk   = (const float*)d_in[8];
    const float* Wv   = (const float*)d_in[9];
    const float* bv   = (const float*)d_in[10];
    const float* Wpos = (const float*)d_in[11];
    const float* Wout = (const float*)d_in[12];
    const float* bout = (const float*)d_in[13];
    const float* ub   = (const float*)d_in[14];
    const float* vb   = (const float*)d_in[15];

    const size_t NBS = (size_t)BB * SS * DD;   // 4194304
    const size_t NP  = (size_t)PP * DD;        // 1048064
    const size_t NW  = (size_t)DD * DD;        // 262144

    ushort_t* wt   = (ushort_t*)d_ws;          // 5 transposed weights
    ushort_t* qu   = wt + 5 * NW;
    ushort_t* qv   = qu + NBS;
    ushort_t* kbuf = qv + NBS;
    ushort_t* vtb  = kbuf + NBS;               // V^T [bh][c][s]
    ushort_t* pbuf = vtb + NBS;                // [h][u][c]
    ushort_t* xg   = pbuf + NP;

    ushort_t* WtO = wt + 4 * NW;

    wtrans_kernel<<<dim3(320), dim3(256), 0, stream>>>(Wq, Wk, Wv, Wpos, Wout, wt);

    qkvpos_kernel<<<dim3(1664), dim3(256), 0, stream>>>(
        query, key_, value, pos, wt, bq, bk, bv, ub, vb,
        qu, qv, kbuf, vtb, pbuf);

    attn_kernel<<<dim3(64, 8), dim3(512), 0, stream>>>(qu, qv, kbuf, vtb, pbuf, mask, xg);

    outproj_kernel<<<dim3(512), dim3(256), 0, stream>>>(xg, WtO, bout, (float*)d_out);
}